// Round 4
// baseline (9.687 us; speedup 1.0000x reference)
//
#include <hip/hip_runtime.h>
#include <math.h>

namespace {

constexpr float P_BF = 0.02f;
constexpr float P_DP = 0.03f;

// Combined Bloch rotation of Rot(w3) ∘ Rot(x3), each = RZ(om) RY(th) RZ(ph).
// R = Rz(ow) Ry(tw) Rz(pw + ox) Ry(tx) Rz(px)   — 5 fast sincos.
__device__ __forceinline__ void rot3_pair(const float* __restrict__ x3,
                                          const float* __restrict__ w3,
                                          float R[3][3]){
  float s1,c1, s2,c2, s3,c3, s4,c4, s5,c5;
  __sincosf(x3[0], &s1, &c1);            // px
  __sincosf(x3[1], &s2, &c2);            // tx
  __sincosf(w3[0] + x3[2], &s3, &c3);    // pw + ox (merged)
  __sincosf(w3[1], &s4, &c4);            // tw
  __sincosf(w3[2], &s5, &c5);            // ow
  // A = Ry(tw) Rz(pw+ox) Ry(tx)
  float a00 = c4*c3*c2 - s4*s2, a01 = -c4*s3, a02 = c4*c3*s2 + s4*c2;
  float a10 = s3*c2,            a11 =  c3,    a12 = s3*s2;
  float a20 = -s4*c3*c2 - c4*s2, a21 = s4*s3, a22 = -s4*c3*s2 + c4*c2;
  // R = Rz(ow) A Rz(px)
  float b00 = c5*a00 - s5*a10, b01 = c5*a01 - s5*a11, b02 = c5*a02 - s5*a12;
  float b10 = s5*a00 + c5*a10, b11 = s5*a01 + c5*a11, b12 = s5*a02 + c5*a12;
  R[0][0] = b00*c1 + b01*s1;  R[0][1] = -b00*s1 + b01*c1;  R[0][2] = b02;
  R[1][0] = b10*c1 + b11*s1;  R[1][1] = -b10*s1 + b11*c1;  R[1][2] = b12;
  R[2][0] = a20*c1 + a21*s1;  R[2][1] = -a20*s1 + a21*c1;  R[2][2] = a22;
}

// Full 4x4 PTM of one wire step: ampdamp(sigmoid(x0)) ∘ depol ∘ bitflip ∘ Rot(w3) ∘ Rot(x3)
__device__ __forceinline__ void wire_ptm(const float* __restrict__ x3,
                                         const float* __restrict__ w3,
                                         float M[4][4]){
  float R[3][3];
  rot3_pair(x3, w3, R);
  float g  = 1.f/(1.f + __expf(-x3[0]));
  float sq = sqrtf(fmaxf(1.f-g,0.f));
  const float c = 1.f - 4.f*P_DP/3.f;
  const float b = 1.f - 2.f*P_BF;
  M[0][0]=1.f; M[0][1]=0.f; M[0][2]=0.f; M[0][3]=0.f;
  M[1][0]=0.f; M[2][0]=0.f; M[3][0]=g;
  #pragma unroll
  for (int j=0;j<3;++j){
    M[1][j+1] = sq*c*R[0][j];
    M[2][j+1] = sq*c*b*R[1][j];
    M[3][j+1] = (1.f-g)*c*b*R[2][j];
  }
}

// One block per batch element. Phase 1: lanes 0..23 build the 24 PTMs (blk,wire)
// into LDS. Phase 2: lanes 0..7 contract the light-cone for Z_iw.
__global__ __launch_bounds__(64) void pqc_ptm3(const float* __restrict__ xg,
                                               const float* __restrict__ wgt,
                                               float* __restrict__ outg){
  __shared__ float Ms[3][8][4][4];
  const int r = (int)blockIdx.x;
  const int t = (int)threadIdx.x;
  const float* xr = xg + r*24;

  if (t < 24){
    const int blk = t>>3, wire = t&7;
    float M[4][4];
    wire_ptm(xr + 3*wire, wgt + (blk*8 + wire)*3, M);
    #pragma unroll
    for (int a=0;a<4;++a)
      #pragma unroll
      for (int b=0;b<4;++b) Ms[blk][wire][a][b] = M[a][b];
  }
  __syncthreads();

  if (t < 8){
    const int iw = t;
    const float cdp = 1.f - 4.f*P_DP/3.f;
    const float bbf = 1.f - 2.f*P_BF;
    const float nd1 = cdp, nd2 = cdp*bbf, nd3 = cdp*bbf;

    const bool has_l = iw>=1, has_r = iw<=6;
    const bool cz_s0 = iw>=2, cz_s1 = has_l, cz_s2 = has_r, cz_s3 = iw<=5;
    const int wl  = has_l ? iw-1 : 0;
    const int wr  = has_r ? iw+1 : 7;
    const int wll = cz_s0 ? iw-2 : 0;
    const int wrr = cz_s3 ? iw+2 : 7;

    float a1[4];
    #pragma unroll
    for (int q=0;q<4;++q) a1[q] = Ms[2][iw][3][q];
    if (iw==7){ a1[1]*=nd1; a1[2]*=nd2; a1[3]*=nd3; }

    float L[4], Rv[4];
    #pragma unroll
    for (int q=0;q<4;++q){
      L[q]  = has_l ? Ms[1][wl][3][q] : (q==0?1.f:0.f);
      Rv[q] = has_r ? Ms[1][wr][3][q] : (q==0?1.f:0.f);
    }
    float A[4], B[4];
    #pragma unroll
    for (int y=0;y<4;++y){
      A[y] = a1[0]*Ms[1][iw][0][y] + a1[3]*Ms[1][iw][3][y];
      B[y] = a1[1]*Ms[1][iw][1][y] + a1[2]*Ms[1][iw][2][y];
    }
    B[0] = 0.f;

    if (iw==7){
      A[1]*=nd1; A[2]*=nd2; A[3]*=nd3;
      B[1]*=nd1; B[2]*=nd2; B[3]*=nd3;
    }
    if (iw==6){ Rv[1]*=nd1; Rv[2]*=nd2; Rv[3]*=nd3; }

    float m1[4], m2[4], m3[4];
    #pragma unroll
    for (int q=0;q<4;++q){
      m2[q] = Ms[0][iw][q][0] + Ms[0][iw][q][3];
      m1[q] = Ms[0][wl][q][0] + Ms[0][wl][q][3];
      m3[q] = Ms[0][wr][q][0] + Ms[0][wr][q][3];
    }
    const float m0z = Ms[0][wll][3][0] + Ms[0][wll][3][3];
    const float m4z = Ms[0][wrr][3][0] + Ms[0][wrr][3][3];

    float out = 0.f;

    // Term1: separable part dx0*dz0*A[y]
    #pragma unroll
    for (int p2=0;p2<4;++p2){
      float tv = A[p2]*m2[p2];
      if (p2==1||p2==2){
        tv *= cz_s1 ? m1[3] : 1.f;
        tv *= cz_s2 ? m3[3] : 1.f;
      }
      out += tv;
    }

    // Term2: L[p1]*B[p2]*Rv[p3] with CZ signed basis maps
    #pragma unroll
    for (int p1=0;p1<4;++p1){
      const bool in1 = (p1==1)||(p1==2);
      const float v0 = (cz_s0 && in1) ? m0z : 1.f;
      const float lp = L[p1]*v0;
      #pragma unroll
      for (int p2=1;p2<4;++p2){
        const bool in2 = (p2==1)||(p2==2);
        const float q1v  = (cz_s1 && in2) ? m1[p1^3] : m1[p1];
        const bool  f1   = cz_s1 && in1;
        const float sgn1 = (cz_s1 && in1 && in2 && (p1!=p2)) ? -1.f : 1.f;
        const float base = lp * B[p2] * q1v * sgn1;
        #pragma unroll
        for (int p3=0;p3<4;++p3){
          const bool in3 = (p3==1)||(p3==2);
          const float v4 = (cz_s3 && in3) ? m4z : 1.f;
          const bool  f2 = cz_s2 && in3;
          const float q2v = (f1!=f2) ? m2[p2^3] : m2[p2];
          const float q3v = (cz_s2 && in2) ? m3[p3^3] : m3[p3];
          const bool  neq = f1 ? ((p2^3)!=p3) : (p2!=p3);
          const float sgn2 = (cz_s2 && in2 && in3 && neq) ? -1.f : 1.f;
          out += base * Rv[p3] * v4 * q2v * q3v * sgn2;
        }
      }
    }

    outg[r*8 + iw] = out;
  }
}

} // namespace

extern "C" void kernel_launch(void* const* d_in, const int* in_sizes, int n_in,
                              void* d_out, int out_size, void* d_ws, size_t ws_size,
                              hipStream_t stream) {
  (void)in_sizes; (void)n_in; (void)d_ws; (void)ws_size; (void)out_size;
  const float* x = (const float*)d_in[0];   // [64, 24]
  const float* w = (const float*)d_in[1];   // [3, 8, 3]
  float* out = (float*)d_out;               // [64, 8]
  pqc_ptm3<<<dim3(64), dim3(64), 0, stream>>>(x, w, out);
}